// Round 5
// baseline (1195.412 us; speedup 1.0000x reference)
//
#include <hip/hip_runtime.h>
#include <hip/hip_bf16.h>
#include <cstdint>
#include <cstddef>

#define B 64
#define T 512
#define EMBED 128
#define H 128
#define G4 512          // 4*H
#define HOUT 256        // 2*H (bilstm concat)
#define NUM_CLASSES 10
#define BT (B * T)      // 32768

// ---------------------------------------------------------------------------
// 1) GEMM: C(M,G4) = A(M,K) @ W(K,G4) + bias(G4)
//    BM=128, BN=64, BK=16, 256 threads, 8x4 micro-tile.
//    If xrow != nullptr, A-row m is A[xrow[m], :] (embedding fusion).
// ---------------------------------------------------------------------------
#define BM 128
#define BN 64
#define BK 16

__global__ __launch_bounds__(256) void gemm_bias_kernel(
    const float* __restrict__ A, const int* __restrict__ xrow,
    const float* __restrict__ W, const float* __restrict__ bias,
    float* __restrict__ C, int K)
{
    __shared__ __align__(16) float As[BK][BM + 4];  // transposed: As[k][m]
    __shared__ __align__(16) float Ws[BK][BN + 4];  // Ws[k][n]

    int tid = threadIdx.x;
    int tx = tid & 15;    // N direction, 16 x 4 = 64
    int ty = tid >> 4;    // M direction, 16 x 8 = 128
    int m0 = blockIdx.y * BM;
    int n0 = blockIdx.x * BN;

    // A-row pointers for this thread's two staging rows (fixed across k-tiles)
    int ra = tid >> 2;        // 0..63
    int cq = tid & 3;         // float4 slot in k
    const float* arow0;
    const float* arow1;
    if (xrow) {
        arow0 = A + (size_t)xrow[m0 + ra] * K;
        arow1 = A + (size_t)xrow[m0 + ra + 64] * K;
    } else {
        arow0 = A + (size_t)(m0 + ra) * K;
        arow1 = A + (size_t)(m0 + ra + 64) * K;
    }

    float acc[8][4];
#pragma unroll
    for (int i = 0; i < 8; i++)
#pragma unroll
        for (int j = 0; j < 4; j++) acc[i][j] = 0.f;

    for (int k0 = 0; k0 < K; k0 += BK) {
        // A tile: 128 rows x 16 k (store transposed)
        {
            float4 a = *(const float4*)&arow0[k0 + cq * 4];
            As[cq * 4 + 0][ra] = a.x;
            As[cq * 4 + 1][ra] = a.y;
            As[cq * 4 + 2][ra] = a.z;
            As[cq * 4 + 3][ra] = a.w;
            float4 b = *(const float4*)&arow1[k0 + cq * 4];
            As[cq * 4 + 0][ra + 64] = b.x;
            As[cq * 4 + 1][ra + 64] = b.y;
            As[cq * 4 + 2][ra + 64] = b.z;
            As[cq * 4 + 3][ra + 64] = b.w;
        }
        // W tile: 16 k x 64 n = 256 float4, 1 per thread
        {
            int rw = tid >> 4;                // 0..15
            int cw = tid & 15;
            float4 wv = *(const float4*)&W[(size_t)(k0 + rw) * G4 + n0 + cw * 4];
            *(float4*)&Ws[rw][cw * 4] = wv;
        }
        __syncthreads();

#pragma unroll
        for (int k = 0; k < BK; k++) {
            float4 a0 = *(const float4*)&As[k][ty * 8];
            float4 a1 = *(const float4*)&As[k][ty * 8 + 4];
            float4 w0 = *(const float4*)&Ws[k][tx * 4];
            float av[8] = {a0.x, a0.y, a0.z, a0.w, a1.x, a1.y, a1.z, a1.w};
            float wv[4] = {w0.x, w0.y, w0.z, w0.w};
#pragma unroll
            for (int i = 0; i < 8; i++)
#pragma unroll
                for (int j = 0; j < 4; j++)
                    acc[i][j] = fmaf(av[i], wv[j], acc[i][j]);
        }
        __syncthreads();
    }

    float4 bv = *(const float4*)&bias[n0 + tx * 4];
#pragma unroll
    for (int i = 0; i < 8; i++) {
        int m = m0 + ty * 8 + i;
        float4 o;
        o.x = acc[i][0] + bv.x;
        o.y = acc[i][1] + bv.y;
        o.z = acc[i][2] + bv.z;
        o.w = acc[i][3] + bv.w;
        *(float4*)&C[(size_t)m * G4 + n0 + tx * 4] = o;
    }
}

// ---------------------------------------------------------------------------
// 2) LSTM scan v5: identical to v4 except the in-loop barrier drains LDS
//    ONLY (s_waitcnt lgkmcnt(0) + s_barrier). __syncthreads() would emit
//    s_waitcnt vmcnt(0) before s_barrier, serializing the per-step hout
//    store completion and the xp prefetch into every step (m97 barrier-
//    drain). hout is never re-read in this kernel; xp loads are RAW-
//    protected by compiler vmcnt waits at use -> LDS-only drain is safe.
// ---------------------------------------------------------------------------
__device__ __forceinline__ float fast_sig(float x) {
    // 1/(1+e^-x); inf-safe: e=inf -> rcp(inf)=0
    float e = __expf(-x);
    return __builtin_amdgcn_rcpf(1.f + e);
}

template <int CTRL>
__device__ __forceinline__ float dpp_add(float x) {
    int y = __builtin_amdgcn_mov_dpp(__float_as_int(x), CTRL, 0xF, 0xF, true);
    return x + __int_as_float(y);
}

__device__ __forceinline__ void wg_barrier_lds() {
    asm volatile("s_waitcnt lgkmcnt(0)" ::: "memory");
    __builtin_amdgcn_s_barrier();
}

__global__ __launch_bounds__(1024) __attribute__((amdgpu_waves_per_eu(4, 4)))
void lstm_scan_kernel(
    const float* __restrict__ xp0, const float* __restrict__ xp1,
    const float* __restrict__ Wh0, const float* __restrict__ Wh1,
    const int* __restrict__ x, float* __restrict__ hout)
{
    const int b   = blockIdx.x;
    const int dir = blockIdx.y;  // 0 = forward, 1 = reverse
    const float* __restrict__ xp = dir ? xp1 : xp0;
    const float* __restrict__ Wh = dir ? Wh1 : Wh0;

    const int tid = threadIdx.x;
    const int ks  = tid & 7;     // k-slice 0..7 -> k in [16ks, 16ks+16)
    const int q   = tid >> 3;    // hidden column 0..127

    // weights: Wh[k][c*H+q], k = ks*16 + r  -> 64 named floats, asm-pinned
    const float* wp = Wh + (size_t)(ks * 16) * G4 + q;
#define DECLW(c) \
    float w##c##_0  = wp[c * H +  0 * G4], w##c##_1  = wp[c * H +  1 * G4], \
          w##c##_2  = wp[c * H +  2 * G4], w##c##_3  = wp[c * H +  3 * G4], \
          w##c##_4  = wp[c * H +  4 * G4], w##c##_5  = wp[c * H +  5 * G4], \
          w##c##_6  = wp[c * H +  6 * G4], w##c##_7  = wp[c * H +  7 * G4], \
          w##c##_8  = wp[c * H +  8 * G4], w##c##_9  = wp[c * H +  9 * G4], \
          w##c##_10 = wp[c * H + 10 * G4], w##c##_11 = wp[c * H + 11 * G4], \
          w##c##_12 = wp[c * H + 12 * G4], w##c##_13 = wp[c * H + 13 * G4], \
          w##c##_14 = wp[c * H + 14 * G4], w##c##_15 = wp[c * H + 15 * G4];
    DECLW(0) DECLW(1) DECLW(2) DECLW(3)
#undef DECLW
#define PIN4(a, b_, c_, d_) asm volatile("" : "+v"(a), "+v"(b_), "+v"(c_), "+v"(d_))
#define PINC(c) \
    PIN4(w##c##_0,  w##c##_1,  w##c##_2,  w##c##_3);  \
    PIN4(w##c##_4,  w##c##_5,  w##c##_6,  w##c##_7);  \
    PIN4(w##c##_8,  w##c##_9,  w##c##_10, w##c##_11); \
    PIN4(w##c##_12, w##c##_13, w##c##_14, w##c##_15)
    PINC(0); PINC(1); PINC(2); PINC(3);
#undef PINC
#undef PIN4

    // h: [buf][block ks][16 data + 4 skew]; block bases hit banks
    // {0,20,8,28,16,4,24,12} (mod 32) -> 8 reads partition all banks.
    __shared__ __align__(16) float h_sh[2][8][20];
    __shared__ unsigned char mask_sh[T];

    if (tid < H) h_sh[0][tid >> 4][tid & 15] = 0.f;
    if (tid < T) mask_sh[tid] = (x[(size_t)b * T + tid] != 0) ? 1 : 0;
    float c_reg = 0.f, h_reg = 0.f;
    __syncthreads();

    const int t0 = dir ? T - 1 : 0;
    const ptrdiff_t dstep = dir ? -(ptrdiff_t)G4 : (ptrdiff_t)G4;
    const ptrdiff_t hstep = dir ? -(ptrdiff_t)HOUT : (ptrdiff_t)HOUT;
    // all lanes load (ks&3) -> no exec-masked address OOB, values for ks>=4
    // are discarded by the (ks==c) init selects.
    const float* xptr = xp + ((size_t)b * T + t0) * G4 + (ks & 3) * H + q;
    float*       hptr = hout + ((size_t)b * T + t0) * HOUT + dir * H + q;
    float xp_cur = *xptr;

    int cb = 0;
    int t = t0;
    const int tinc = dir ? -1 : 1;

    for (int s = 0; s < T; s++) {
        float xin = xp_cur;
        if (s + 1 < T) {           // prefetch next step's xp
            xptr += dstep;
            xp_cur = *xptr;
        }

        // partials: a_c = (ks==c ? xp : 0) + sum_r h[16ks+r] * w_c_r
        float a0 = (ks == 0) ? xin : 0.f;
        float a1 = (ks == 1) ? xin : 0.f;
        float a2 = (ks == 2) ? xin : 0.f;
        float a3 = (ks == 3) ? xin : 0.f;

        const float4* hp = (const float4*)&h_sh[cb][ks][0];
        float4 hv0 = hp[0], hv1 = hp[1], hv2 = hp[2], hv3 = hp[3];
#define FMA16(c) \
        a##c = fmaf(hv0.x, w##c##_0,  a##c); a##c = fmaf(hv0.y, w##c##_1,  a##c); \
        a##c = fmaf(hv0.z, w##c##_2,  a##c); a##c = fmaf(hv0.w, w##c##_3,  a##c); \
        a##c = fmaf(hv1.x, w##c##_4,  a##c); a##c = fmaf(hv1.y, w##c##_5,  a##c); \
        a##c = fmaf(hv1.z, w##c##_6,  a##c); a##c = fmaf(hv1.w, w##c##_7,  a##c); \
        a##c = fmaf(hv2.x, w##c##_8,  a##c); a##c = fmaf(hv2.y, w##c##_9,  a##c); \
        a##c = fmaf(hv2.z, w##c##_10, a##c); a##c = fmaf(hv2.w, w##c##_11, a##c); \
        a##c = fmaf(hv3.x, w##c##_12, a##c); a##c = fmaf(hv3.y, w##c##_13, a##c); \
        a##c = fmaf(hv3.z, w##c##_14, a##c); a##c = fmaf(hv3.w, w##c##_15, a##c);
        FMA16(0) FMA16(1) FMA16(2) FMA16(3)
#undef FMA16

        // butterfly over the 8 ks-lanes: xor1, xor2 (quad_perm), then
        // quad<->quad via row_half_mirror (quads uniform after level 2).
        a0 = dpp_add<0xB1>(a0);  a1 = dpp_add<0xB1>(a1);
        a2 = dpp_add<0xB1>(a2);  a3 = dpp_add<0xB1>(a3);
        a0 = dpp_add<0x4E>(a0);  a1 = dpp_add<0x4E>(a1);
        a2 = dpp_add<0x4E>(a2);  a3 = dpp_add<0x4E>(a3);
        a0 = dpp_add<0x141>(a0); a1 = dpp_add<0x141>(a1);
        a2 = dpp_add<0x141>(a2); a3 = dpp_add<0x141>(a3);

        // gates (lane-local, redundant across the octet)
        float ig = fast_sig(a0);
        float fg = fast_sig(a1);
        float gg = 2.f * fast_sig(a2 + a2) - 1.f;   // tanh
        float og = fast_sig(a3);
        float cn = fmaf(fg, c_reg, ig * gg);
        float th = 2.f * fast_sig(cn + cn) - 1.f;   // tanh
        float hn = og * th;

        bool msk = mask_sh[t] != 0;
        c_reg = msk ? cn : c_reg;
        h_reg = msk ? hn : h_reg;

        if (ks == 0) {
            h_sh[cb ^ 1][q >> 4][q & 15] = h_reg;
            *hptr = h_reg;
        }
        hptr += hstep;
        wg_barrier_lds();          // LDS-only drain: vmcnt stays in flight
        cb ^= 1;
        t += tinc;
    }
}

// ---------------------------------------------------------------------------
// 3) pooling: per (b,t) max & mean over 256 channels -> feat (B, 2T)
// ---------------------------------------------------------------------------
__global__ __launch_bounds__(256) void pool_kernel(
    const float* __restrict__ Hin, float* __restrict__ feat)
{
    int wave = threadIdx.x >> 6;
    int lane = threadIdx.x & 63;
    int bt = blockIdx.x * 4 + wave;
    float4 v = *(const float4*)&Hin[(size_t)bt * HOUT + lane * 4];
    float mx = fmaxf(fmaxf(v.x, v.y), fmaxf(v.z, v.w));
    float sm = (v.x + v.y) + (v.z + v.w);
#pragma unroll
    for (int off = 32; off > 0; off >>= 1) {
        mx = fmaxf(mx, __shfl_down(mx, off));
        sm += __shfl_down(sm, off);
    }
    if (lane == 0) {
        int b = bt >> 9;        // /T
        int t = bt & (T - 1);
        feat[(size_t)b * (2 * T) + t]     = mx;
        feat[(size_t)b * (2 * T) + T + t] = sm * (1.f / 256.f);
    }
}

// ---------------------------------------------------------------------------
// 4) FC: out(B,10) = relu(feat(B,1024) @ fcW(1024,10) + fcb)
// ---------------------------------------------------------------------------
__global__ __launch_bounds__(128) void fc_kernel(
    const float* __restrict__ feat, const float* __restrict__ fcW,
    const float* __restrict__ fcb, float* __restrict__ out)
{
    __shared__ float red[2][NUM_CLASSES];
    int b = blockIdx.x, tid = threadIdx.x;
    float acc[NUM_CLASSES];
#pragma unroll
    for (int c = 0; c < NUM_CLASSES; c++) acc[c] = 0.f;
#pragma unroll
    for (int it = 0; it < 8; it++) {
        int k = tid + it * 128;
        float fv = feat[(size_t)b * 1024 + k];
#pragma unroll
        for (int c = 0; c < NUM_CLASSES; c++)
            acc[c] = fmaf(fv, fcW[(size_t)k * NUM_CLASSES + c], acc[c]);
    }
#pragma unroll
    for (int c = 0; c < NUM_CLASSES; c++) {
        float v = acc[c];
        for (int off = 32; off > 0; off >>= 1) v += __shfl_down(v, off);
        if ((tid & 63) == 0) red[tid >> 6][c] = v;
    }
    __syncthreads();
    if (tid < NUM_CLASSES) {
        float v = red[0][tid] + red[1][tid] + fcb[tid];
        out[(size_t)b * NUM_CLASSES + tid] = fmaxf(v, 0.f);
    }
}

// ---------------------------------------------------------------------------
// launch
// ---------------------------------------------------------------------------
extern "C" void kernel_launch(void* const* d_in, const int* in_sizes, int n_in,
                              void* d_out, int out_size, void* d_ws, size_t ws_size,
                              hipStream_t stream)
{
    const int*   x     = (const int*)d_in[0];
    const float* emb   = (const float*)d_in[1];
    const float* Wx_f0 = (const float*)d_in[2];
    const float* Wh_f0 = (const float*)d_in[3];
    const float* b_f0  = (const float*)d_in[4];
    const float* Wx_b0 = (const float*)d_in[5];
    const float* Wh_b0 = (const float*)d_in[6];
    const float* b_b0  = (const float*)d_in[7];
    const float* Wx_f1 = (const float*)d_in[8];
    const float* Wh_f1 = (const float*)d_in[9];
    const float* b_f1  = (const float*)d_in[10];
    const float* Wx_b1 = (const float*)d_in[11];
    const float* Wh_b1 = (const float*)d_in[12];
    const float* b_b1  = (const float*)d_in[13];
    const float* fcW   = (const float*)d_in[14];
    const float* fcb   = (const float*)d_in[15];
    float* out = (float*)d_out;

    char* ws = (char*)d_ws;
    const size_t MB = 1024 * 1024;
    float* H1   = (float*)(ws);                  // 32 MB  (BT x 256)
    float* H0   = (float*)(ws + 32 * MB);        // 32 MB  (BT x 256)
    float* xpF  = (float*)(ws + 64 * MB);        // 64 MB  (BT x 512)
    float* xpB  = (float*)(ws + 128 * MB);       // 64 MB  (BT x 512)
    float* feat = (float*)(ws + 192 * MB);       // 256 KB (B x 1024)

    dim3 ggrid(G4 / BN, BT / BM);  // (8, 256)

    // layer 0 (A-rows gathered from emb on the fly)
    gemm_bias_kernel<<<ggrid, 256, 0, stream>>>(emb, x, Wx_f0, b_f0, xpF, EMBED);
    gemm_bias_kernel<<<ggrid, 256, 0, stream>>>(emb, x, Wx_b0, b_b0, xpB, EMBED);
    lstm_scan_kernel<<<dim3(B, 2), 1024, 0, stream>>>(xpF, xpB, Wh_f0, Wh_b0, x, H0);

    // layer 1 (input = H0, K = 256)
    gemm_bias_kernel<<<ggrid, 256, 0, stream>>>(H0, nullptr, Wx_f1, b_f1, xpF, 2 * H);
    gemm_bias_kernel<<<ggrid, 256, 0, stream>>>(H0, nullptr, Wx_b1, b_b1, xpB, 2 * H);
    lstm_scan_kernel<<<dim3(B, 2), 1024, 0, stream>>>(xpF, xpB, Wh_f1, Wh_b1, x, H1);

    // pooling + FC
    pool_kernel<<<BT / 4, 256, 0, stream>>>(H1, feat);
    fc_kernel<<<B, 128, 0, stream>>>(feat, fcW, fcb, out);
}

// Round 6
// 1051.355 us; speedup vs baseline: 1.1370x; 1.1370x over previous
//
#include <hip/hip_runtime.h>
#include <hip/hip_bf16.h>
#include <cstdint>
#include <cstddef>

#define B 64
#define T 512
#define EMBED 128
#define H 128
#define G4 512          // 4*H
#define HOUT 256        // 2*H (bilstm concat)
#define NUM_CLASSES 10
#define BT (B * T)      // 32768

typedef float v2f __attribute__((ext_vector_type(2)));
typedef float v4f __attribute__((ext_vector_type(4)));

// ---------------------------------------------------------------------------
// 1) GEMM: C(M,G4) = A(M,K) @ W(K,G4) + bias(G4)
//    BM=128, BN=64, BK=16, 256 threads, 8x4 micro-tile.
//    If xrow != nullptr, A-row m is A[xrow[m], :] (embedding fusion).
// ---------------------------------------------------------------------------
#define BM 128
#define BN 64
#define BK 16

__global__ __launch_bounds__(256) void gemm_bias_kernel(
    const float* __restrict__ A, const int* __restrict__ xrow,
    const float* __restrict__ W, const float* __restrict__ bias,
    float* __restrict__ C, int K)
{
    __shared__ __align__(16) float As[BK][BM + 4];  // transposed: As[k][m]
    __shared__ __align__(16) float Ws[BK][BN + 4];  // Ws[k][n]

    int tid = threadIdx.x;
    int tx = tid & 15;    // N direction, 16 x 4 = 64
    int ty = tid >> 4;    // M direction, 16 x 8 = 128
    int m0 = blockIdx.y * BM;
    int n0 = blockIdx.x * BN;

    // A-row pointers for this thread's two staging rows (fixed across k-tiles)
    int ra = tid >> 2;        // 0..63
    int cq = tid & 3;         // float4 slot in k
    const float* arow0;
    const float* arow1;
    if (xrow) {
        arow0 = A + (size_t)xrow[m0 + ra] * K;
        arow1 = A + (size_t)xrow[m0 + ra + 64] * K;
    } else {
        arow0 = A + (size_t)(m0 + ra) * K;
        arow1 = A + (size_t)(m0 + ra + 64) * K;
    }

    float acc[8][4];
#pragma unroll
    for (int i = 0; i < 8; i++)
#pragma unroll
        for (int j = 0; j < 4; j++) acc[i][j] = 0.f;

    for (int k0 = 0; k0 < K; k0 += BK) {
        // A tile: 128 rows x 16 k (store transposed)
        {
            float4 a = *(const float4*)&arow0[k0 + cq * 4];
            As[cq * 4 + 0][ra] = a.x;
            As[cq * 4 + 1][ra] = a.y;
            As[cq * 4 + 2][ra] = a.z;
            As[cq * 4 + 3][ra] = a.w;
            float4 b = *(const float4*)&arow1[k0 + cq * 4];
            As[cq * 4 + 0][ra + 64] = b.x;
            As[cq * 4 + 1][ra + 64] = b.y;
            As[cq * 4 + 2][ra + 64] = b.z;
            As[cq * 4 + 3][ra + 64] = b.w;
        }
        // W tile: 16 k x 64 n = 256 float4, 1 per thread
        {
            int rw = tid >> 4;                // 0..15
            int cw = tid & 15;
            float4 wv = *(const float4*)&W[(size_t)(k0 + rw) * G4 + n0 + cw * 4];
            *(float4*)&Ws[rw][cw * 4] = wv;
        }
        __syncthreads();

#pragma unroll
        for (int k = 0; k < BK; k++) {
            float4 a0 = *(const float4*)&As[k][ty * 8];
            float4 a1 = *(const float4*)&As[k][ty * 8 + 4];
            float4 w0 = *(const float4*)&Ws[k][tx * 4];
            float av[8] = {a0.x, a0.y, a0.z, a0.w, a1.x, a1.y, a1.z, a1.w};
            float wv[4] = {w0.x, w0.y, w0.z, w0.w};
#pragma unroll
            for (int i = 0; i < 8; i++)
#pragma unroll
                for (int j = 0; j < 4; j++)
                    acc[i][j] = fmaf(av[i], wv[j], acc[i][j]);
        }
        __syncthreads();
    }

    float4 bv = *(const float4*)&bias[n0 + tx * 4];
#pragma unroll
    for (int i = 0; i < 8; i++) {
        int m = m0 + ty * 8 + i;
        float4 o;
        o.x = acc[i][0] + bv.x;
        o.y = acc[i][1] + bv.y;
        o.z = acc[i][2] + bv.z;
        o.w = acc[i][3] + bv.w;
        *(float4*)&C[(size_t)m * G4 + n0 + tx * 4] = o;
    }
}

// ---------------------------------------------------------------------------
// 2) LSTM scan v6: one WG (512 threads, 8 waves) per (batch, direction).
//    tid = q*4 + ks: thread computes z for ALL 4 gate columns of q over
//    k in [32ks, 32ks+32), using v_pk_fma_f32 (2 MACs/instr, packed
//    along k: acc.lo = even k, acc.hi = odd k; one horizontal add at end).
//    - 64 weight pairs (128 VGPR) named + asm-pinned; waves_per_eu(2,2).
//    - h in 4 skewed 36-float LDS blocks -> wave's 4 b128 addresses hit
//      disjoint bank groups; 16-lane same-address broadcast.
//    - ks-quad combine: 2 DPP quad_perm butterfly levels.
//    - LDS-only barrier drain (lgkmcnt) per step.
// ---------------------------------------------------------------------------
__device__ __forceinline__ float fast_sig(float x) {
    // 1/(1+e^-x); inf-safe: e=inf -> rcp(inf)=0
    float e = __expf(-x);
    return __builtin_amdgcn_rcpf(1.f + e);
}

template <int CTRL>
__device__ __forceinline__ float dpp_add(float x) {
    int y = __builtin_amdgcn_mov_dpp(__float_as_int(x), CTRL, 0xF, 0xF, true);
    return x + __int_as_float(y);
}

__device__ __forceinline__ void wg_barrier_lds() {
    asm volatile("s_waitcnt lgkmcnt(0)" ::: "memory");
    __builtin_amdgcn_s_barrier();
}

#define PKFMA(acc, h2, w2) \
    asm("v_pk_fma_f32 %0, %1, %2, %0" : "+v"(acc) : "v"(h2), "v"(w2))

__global__ __launch_bounds__(512) __attribute__((amdgpu_waves_per_eu(2, 2)))
void lstm_scan_kernel(
    const float* __restrict__ xp0, const float* __restrict__ xp1,
    const float* __restrict__ Wh0, const float* __restrict__ Wh1,
    const int* __restrict__ x, float* __restrict__ hout)
{
    const int b   = blockIdx.x;
    const int dir = blockIdx.y;  // 0 = forward, 1 = reverse
    const float* __restrict__ xp = dir ? xp1 : xp0;
    const float* __restrict__ Wh = dir ? Wh1 : Wh0;

    const int tid = threadIdx.x;
    const int ks  = tid & 3;     // k-slice 0..3 -> k in [32ks, 32ks+32)
    const int q   = tid >> 2;    // hidden column 0..127

    // weights: pair p of gate c = (Wh[32ks+2p][cH+q], Wh[32ks+2p+1][cH+q])
    const float* wp = Wh + (size_t)(ks * 32) * G4 + q;
#define LDP(c, p) v2f w##c##_##p = { wp[(2 * p) * G4 + c * H], \
                                     wp[(2 * p + 1) * G4 + c * H] }
#define DECLC(c) \
    LDP(c, 0);  LDP(c, 1);  LDP(c, 2);  LDP(c, 3);  \
    LDP(c, 4);  LDP(c, 5);  LDP(c, 6);  LDP(c, 7);  \
    LDP(c, 8);  LDP(c, 9);  LDP(c, 10); LDP(c, 11); \
    LDP(c, 12); LDP(c, 13); LDP(c, 14); LDP(c, 15);
    DECLC(0) DECLC(1) DECLC(2) DECLC(3)
#undef DECLC
#undef LDP
#define PIN4(a, b_, c_, d_) asm volatile("" : "+v"(a), "+v"(b_), "+v"(c_), "+v"(d_))
#define PINC(c) \
    PIN4(w##c##_0,  w##c##_1,  w##c##_2,  w##c##_3);  \
    PIN4(w##c##_4,  w##c##_5,  w##c##_6,  w##c##_7);  \
    PIN4(w##c##_8,  w##c##_9,  w##c##_10, w##c##_11); \
    PIN4(w##c##_12, w##c##_13, w##c##_14, w##c##_15)
    PINC(0); PINC(1); PINC(2); PINC(3);
#undef PINC
#undef PIN4

    // h: [buf][block ks][32 data + 4 skew]; block bases at banks
    // {0,4,8,12} (buf 0) / {16,20,24,28} (buf 1) -> wave's 4 distinct
    // b128 addresses are bank-disjoint at every kk.
    __shared__ __align__(16) float h_sh[2][4][36];
    __shared__ unsigned char mask_sh[T];

    if (tid < H) { h_sh[0][tid >> 5][tid & 31] = 0.f; }
    mask_sh[tid] = (x[(size_t)b * T + tid] != 0) ? 1 : 0;  // blockDim==T==512
    float c_reg = 0.f, h_reg = 0.f;
    __syncthreads();

    const int t0 = dir ? T - 1 : 0;
    const ptrdiff_t dstep = dir ? -(ptrdiff_t)G4 : (ptrdiff_t)G4;
    const ptrdiff_t hstep = dir ? -(ptrdiff_t)HOUT : (ptrdiff_t)HOUT;
    const float* xptr = xp + ((size_t)b * T + t0) * G4 + ks * H + q;
    float*       hptr = hout + ((size_t)b * T + t0) * HOUT + dir * H + q;
    float xp_cur = *xptr;

    int cb = 0;
    int t = t0;
    const int tinc = dir ? -1 : 1;

    for (int s = 0; s < T; s++) {
        float xin = xp_cur;
        if (s + 1 < T) {           // prefetch next step's xp
            xptr += dstep;
            xp_cur = *xptr;
        }

        // packed partials: acc_c.lo = even-k MACs, acc_c.hi = odd-k MACs
        v2f acc0 = { (ks == 0) ? xin : 0.f, 0.f };
        v2f acc1 = { (ks == 1) ? xin : 0.f, 0.f };
        v2f acc2 = { (ks == 2) ? xin : 0.f, 0.f };
        v2f acc3 = { (ks == 3) ? xin : 0.f, 0.f };

        const v4f* hp = (const v4f*)&h_sh[cb][ks][0];
#define STEP4(kk, pA, pB) { \
        v4f hv = hp[kk]; \
        v2f h01 = __builtin_shufflevector(hv, hv, 0, 1); \
        v2f h23 = __builtin_shufflevector(hv, hv, 2, 3); \
        PKFMA(acc0, h01, w0_##pA); PKFMA(acc0, h23, w0_##pB); \
        PKFMA(acc1, h01, w1_##pA); PKFMA(acc1, h23, w1_##pB); \
        PKFMA(acc2, h01, w2_##pA); PKFMA(acc2, h23, w2_##pB); \
        PKFMA(acc3, h01, w3_##pA); PKFMA(acc3, h23, w3_##pB); }
        STEP4(0, 0, 1)   STEP4(1, 2, 3)   STEP4(2, 4, 5)   STEP4(3, 6, 7)
        STEP4(4, 8, 9)   STEP4(5, 10, 11) STEP4(6, 12, 13) STEP4(7, 14, 15)
#undef STEP4

        float a0 = acc0.x + acc0.y;
        float a1 = acc1.x + acc1.y;
        float a2 = acc2.x + acc2.y;
        float a3 = acc3.x + acc3.y;

        // butterfly over the 4 ks-lanes (quad_perm DPP): xor1, xor2
        a0 = dpp_add<0xB1>(a0); a1 = dpp_add<0xB1>(a1);
        a2 = dpp_add<0xB1>(a2); a3 = dpp_add<0xB1>(a3);
        a0 = dpp_add<0x4E>(a0); a1 = dpp_add<0x4E>(a1);
        a2 = dpp_add<0x4E>(a2); a3 = dpp_add<0x4E>(a3);

        // gates (lane-local, redundant across the quad)
        float ig = fast_sig(a0);
        float fg = fast_sig(a1);
        float gg = 2.f * fast_sig(a2 + a2) - 1.f;   // tanh
        float og = fast_sig(a3);
        float cn = fmaf(fg, c_reg, ig * gg);
        float th = 2.f * fast_sig(cn + cn) - 1.f;   // tanh
        float hn = og * th;

        bool msk = mask_sh[t] != 0;
        c_reg = msk ? cn : c_reg;
        h_reg = msk ? hn : h_reg;

        if (ks == 0) {
            h_sh[cb ^ 1][q >> 5][q & 31] = h_reg;
            *hptr = h_reg;
        }
        hptr += hstep;
        wg_barrier_lds();          // LDS-only drain: vmcnt stays in flight
        cb ^= 1;
        t += tinc;
    }
}

// ---------------------------------------------------------------------------
// 3) pooling: per (b,t) max & mean over 256 channels -> feat (B, 2T)
// ---------------------------------------------------------------------------
__global__ __launch_bounds__(256) void pool_kernel(
    const float* __restrict__ Hin, float* __restrict__ feat)
{
    int wave = threadIdx.x >> 6;
    int lane = threadIdx.x & 63;
    int bt = blockIdx.x * 4 + wave;
    float4 v = *(const float4*)&Hin[(size_t)bt * HOUT + lane * 4];
    float mx = fmaxf(fmaxf(v.x, v.y), fmaxf(v.z, v.w));
    float sm = (v.x + v.y) + (v.z + v.w);
#pragma unroll
    for (int off = 32; off > 0; off >>= 1) {
        mx = fmaxf(mx, __shfl_down(mx, off));
        sm += __shfl_down(sm, off);
    }
    if (lane == 0) {
        int b = bt >> 9;        // /T
        int t = bt & (T - 1);
        feat[(size_t)b * (2 * T) + t]     = mx;
        feat[(size_t)b * (2 * T) + T + t] = sm * (1.f / 256.f);
    }
}

// ---------------------------------------------------------------------------
// 4) FC: out(B,10) = relu(feat(B,1024) @ fcW(1024,10) + fcb)
// ---------------------------------------------------------------------------
__global__ __launch_bounds__(128) void fc_kernel(
    const float* __restrict__ feat, const float* __restrict__ fcW,
    const float* __restrict__ fcb, float* __restrict__ out)
{
    __shared__ float red[2][NUM_CLASSES];
    int b = blockIdx.x, tid = threadIdx.x;
    float acc[NUM_CLASSES];
#pragma unroll
    for (int c = 0; c < NUM_CLASSES; c++) acc[c] = 0.f;
#pragma unroll
    for (int it = 0; it < 8; it++) {
        int k = tid + it * 128;
        float fv = feat[(size_t)b * 1024 + k];
#pragma unroll
        for (int c = 0; c < NUM_CLASSES; c++)
            acc[c] = fmaf(fv, fcW[(size_t)k * NUM_CLASSES + c], acc[c]);
    }
#pragma unroll
    for (int c = 0; c < NUM_CLASSES; c++) {
        float v = acc[c];
        for (int off = 32; off > 0; off >>= 1) v += __shfl_down(v, off);
        if ((tid & 63) == 0) red[tid >> 6][c] = v;
    }
    __syncthreads();
    if (tid < NUM_CLASSES) {
        float v = red[0][tid] + red[1][tid] + fcb[tid];
        out[(size_t)b * NUM_CLASSES + tid] = fmaxf(v, 0.f);
    }
}

// ---------------------------------------------------------------------------
// launch
// ---------------------------------------------------------------------------
extern "C" void kernel_launch(void* const* d_in, const int* in_sizes, int n_in,
                              void* d_out, int out_size, void* d_ws, size_t ws_size,
                              hipStream_t stream)
{
    const int*   x     = (const int*)d_in[0];
    const float* emb   = (const float*)d_in[1];
    const float* Wx_f0 = (const float*)d_in[2];
    const float* Wh_f0 = (const float*)d_in[3];
    const float* b_f0  = (const float*)d_in[4];
    const float* Wx_b0 = (const float*)d_in[5];
    const float* Wh_b0 = (const float*)d_in[6];
    const float* b_b0  = (const float*)d_in[7];
    const float* Wx_f1 = (const float*)d_in[8];
    const float* Wh_f1 = (const float*)d_in[9];
    const float* b_f1  = (const float*)d_in[10];
    const float* Wx_b1 = (const float*)d_in[11];
    const float* Wh_b1 = (const float*)d_in[12];
    const float* b_b1  = (const float*)d_in[13];
    const float* fcW   = (const float*)d_in[14];
    const float* fcb   = (const float*)d_in[15];
    float* out = (float*)d_out;

    char* ws = (char*)d_ws;
    const size_t MB = 1024 * 1024;
    float* H1   = (float*)(ws);                  // 32 MB  (BT x 256)
    float* H0   = (float*)(ws + 32 * MB);        // 32 MB  (BT x 256)
    float* xpF  = (float*)(ws + 64 * MB);        // 64 MB  (BT x 512)
    float* xpB  = (float*)(ws + 128 * MB);       // 64 MB  (BT x 512)
    float* feat = (float*)(ws + 192 * MB);       // 256 KB (B x 1024)

    dim3 ggrid(G4 / BN, BT / BM);  // (8, 256)

    // layer 0 (A-rows gathered from emb on the fly)
    gemm_bias_kernel<<<ggrid, 256, 0, stream>>>(emb, x, Wx_f0, b_f0, xpF, EMBED);
    gemm_bias_kernel<<<ggrid, 256, 0, stream>>>(emb, x, Wx_b0, b_b0, xpB, EMBED);
    lstm_scan_kernel<<<dim3(B, 2), 512, 0, stream>>>(xpF, xpB, Wh_f0, Wh_b0, x, H0);

    // layer 1 (input = H0, K = 256)
    gemm_bias_kernel<<<ggrid, 256, 0, stream>>>(H0, nullptr, Wx_f1, b_f1, xpF, 2 * H);
    gemm_bias_kernel<<<ggrid, 256, 0, stream>>>(H0, nullptr, Wx_b1, b_b1, xpB, 2 * H);
    lstm_scan_kernel<<<dim3(B, 2), 512, 0, stream>>>(xpF, xpB, Wh_f1, Wh_b1, x, H1);

    // pooling + FC
    pool_kernel<<<BT / 4, 256, 0, stream>>>(H1, feat);
    fc_kernel<<<B, 128, 0, stream>>>(feat, fcW, fcb, out);
}